// Round 8
// baseline (501.878 us; speedup 1.0000x reference)
//
#include <hip/hip_runtime.h>
#include <hip/hip_bf16.h>

#define HH 4
#define NR 20000
#define DIN 257
#define DS 256
#define MF 64
#define KP 288   // padded K for bf16 staging; k=257 is the bias-1 slot
#define LTP 272  // lastT padded d-rows
#define ZST 276  // fuse3 LDS z-tile row stride
#define LKC 25   // last3 split-K: 25 grid x 25 chunks x 32 rows = 20000

typedef __bf16 bf16;
typedef bf16 bf16x8 __attribute__((ext_vector_type(8)));
typedef bf16 bf16x4 __attribute__((ext_vector_type(4)));
typedef bf16 bf16x2 __attribute__((ext_vector_type(2)));
typedef float f32x4 __attribute__((ext_vector_type(4)));
typedef unsigned int u32x4 __attribute__((ext_vector_type(4)));

// ---------------------------------------------------------------------------
// conversions
// ---------------------------------------------------------------------------
__global__ void cvt_x_kernel(const float* __restrict__ xA, const float* __restrict__ xB,
                             bf16* __restrict__ xbA, bf16* __restrict__ xbB) {
  const int n = blockIdx.x, k = threadIdx.x;  // 288 threads, y = side
  const float* x = blockIdx.y ? xB : xA;
  bf16* xb = blockIdx.y ? xbB : xbA;
  bf16 v = (bf16)0.f;
  if (k < DIN) v = (bf16)x[(long)n * DIN + k];
  else if (k == DIN) v = (bf16)1.f;  // bias-1 slot (WbT pads are 0 there)
  xb[(long)n * KP + k] = v;
}

__global__ void cvt_w_kernel(const float* __restrict__ Wq, const float* __restrict__ Wk,
                             const float* __restrict__ Wv, bf16* __restrict__ WbTq,
                             bf16* __restrict__ WbTk, bf16* __restrict__ WbTv) {
  const int which = blockIdx.y;
  const int h = blockIdx.x >> 8, n = blockIdx.x & 255, k = threadIdx.x;
  const float* W = which == 0 ? Wq : (which == 1 ? Wk : Wv);
  bf16* o = which == 0 ? WbTq : (which == 1 ? WbTk : WbTv);
  o[((long)h * 256 + n) * KP + k] =
      (k < DIN) ? (bf16)W[((long)h * DIN + k) * DS + n] : (bf16)0.f;
}

// WpT[(which*HH+h)][m][k] = sum_d W[h][k][d]*proj[d][m]; k=257 row = b.proj
__global__ void cvt_wp_kernel(const float* __restrict__ Wq, const float* __restrict__ Wk,
                              const float* __restrict__ bq, const float* __restrict__ bk,
                              const float* __restrict__ proj, bf16* __restrict__ WpT) {
  const int k = blockIdx.x, h = blockIdx.y, which = blockIdx.z, m = threadIdx.x;
  const float* W = which ? Wk : Wq;
  const float* bb = which ? bk : bq;
  float acc = 0.f;
  if (k < DIN) {
    const float* wr = W + ((long)h * DIN + k) * DS;
#pragma unroll 8
    for (int d = 0; d < DS; d++) acc = fmaf(wr[d], proj[(long)d * MF + m], acc);
  } else if (k == DIN) {
    const float* br = bb + (long)h * DS;
#pragma unroll 8
    for (int d = 0; d < DS; d++) acc = fmaf(br[d], proj[(long)d * MF + m], acc);
  }
  WpT[(((long)which * HH + h) * MF + m) * KP + k] = (bf16)acc;
}

// ---------------------------------------------------------------------------
// async global->LDS 16B helper
// ---------------------------------------------------------------------------
__device__ __forceinline__ void gl_lds16(const bf16* g, bf16* l) {
  __builtin_amdgcn_global_load_lds(
      (const __attribute__((address_space(1))) unsigned int*)g,
      (__attribute__((address_space(3))) unsigned int*)l, 16, 0, 0);
}

// ---------------------------------------------------------------------------
// proj4: LDS-staged double-buffered projection GEMM. grid (24, 313).
// blockIdx.x = zh (z*4+h, FAST dim -> A-tile L2 reuse across the 8 XCDs).
// z: 0=value-u 1=value-i 2=q-u 3=k-u 4=q-i 5=k-i
// Block = 64 rows x 256 cols, 4 waves; wave w owns cols w*64..w*64+63, acc 4x4.
// TRANSPOSED STAGING (R8): staging lane l fetches (row=l&15, chunk=l>>4), so
// element (r, 8-col chunk c) lands at LDS slot c*16+r. Fragment read for lane
// (m16,q) is then byte lane*16 -- perfectly linear, ZERO bank conflicts (old
// layout was an 8-way conflict: byte m16*64+q*16, 8.65M conflict cycles).
// Global side: wave still touches the same 16 aligned 64B segments/instr.
// Sync structure identical to the R5-verified kernel (one __syncthreads/chunk).
// ---------------------------------------------------------------------------
__global__ __launch_bounds__(256) void proj4_kernel(
    const bf16* __restrict__ xbA, const bf16* __restrict__ xbB,
    const bf16* __restrict__ WbTq, const bf16* __restrict__ WbTk,
    const bf16* __restrict__ WbTv,
    const float* __restrict__ bq, const float* __restrict__ bk,
    const float* __restrict__ bv,
    float* __restrict__ voA, float* __restrict__ voB, float* __restrict__ fr)
{
  // 40 KB carved LDS: A dbuf [2][64*32] bf16 = 8 KB, B dbuf [2][256*32] = 32 KB.
  // rs[64][4] overlays the A buffer after the K-loop (barrier-protected).
  __shared__ __align__(16) char smem[40960];
  bf16* Ab = (bf16*)smem;              // 2 * 2048 elems
  bf16* Bb = (bf16*)(smem + 8192);     // 2 * 8192 elems
  float (*rs)[4] = (float(*)[4])smem;

  const int t = threadIdx.x;
  const int zh = blockIdx.x;
  const int h = zh & 3;
  const int z = zh >> 2;
  const int n0 = blockIdx.y * 64;
  const bf16* xb = (z == 1 || z >= 4) ? xbB : xbA;
  const bf16* WbT = (z < 2) ? WbTv : ((z == 2 || z == 4) ? WbTq : WbTk);
  const float* bsel = (z < 2) ? bv : ((z == 2 || z == 4) ? bq : bk);
  const int w = t >> 6, lane = t & 63;
  const int m16 = lane & 15, q = lane >> 4;
  const bf16* wbh = WbT + (long)h * 256 * KP;

  // transposed staging geometry: wave w stages rows w*16..w*16+15 of each
  // 64-row panel; lane l covers row w*16+(l&15), col (l>>4)*8.
  // LDS slot = lane*16B  =>  element (r, chunk c) at slot c*16+r.
  const int rsubT = lane & 15;
  const int cbT = (lane >> 4) * 8;
  const bf16* gA = xb + (long)min(n0 + w * 16 + rsubT, NR - 1) * KP + cbT;
  const bf16* gB = wbh + (long)(w * 16 + rsubT) * KP + cbT;

#define STAGE(buf, c)                                                        \
  do {                                                                       \
    const int _k0 = (c) * 32;                                                \
    gl_lds16(gA + _k0, Ab + (buf) * 2048 + w * 512);                         \
    _Pragma("unroll")                                                        \
    for (int e = 0; e < 4; e++)                                              \
      gl_lds16(gB + (long)e * 64 * KP + _k0,                                 \
               Bb + (buf) * 8192 + e * 2048 + w * 512);                      \
  } while (0)

  f32x4 acc[4][4] = {};
  STAGE(0, 0);

  for (int c = 0; c < 9; c++) {
    const int cur = c & 1;
    __syncthreads();  // drains vmcnt -> buf[cur] landed; all waves done with buf[1-cur]
    if (c < 8) STAGE(1 - cur, c + 1);

    // linear reads: lane (m16,q) reads slot (q*16+m16) of its panel.
    const int fslot = (q * 16 + m16) * 8;
    bf16x8 af[4], bfj[4];
#pragma unroll
    for (int i = 0; i < 4; i++)
      af[i] = *(const bf16x8*)(Ab + cur * 2048 + i * 512 + fslot);
#pragma unroll
    for (int j = 0; j < 4; j++)
      bfj[j] = *(const bf16x8*)(Bb + cur * 8192 + w * 2048 + j * 512 + fslot);
#pragma unroll
    for (int i = 0; i < 4; i++)
#pragma unroll
      for (int j = 0; j < 4; j++)
        acc[i][j] = __builtin_amdgcn_mfma_f32_16x16x32_bf16(af[i], bfj[j], acc[i][j], 0, 0, 0);
  }
#undef STAGE

  __syncthreads();  // all waves done reading Ab before rs overlays it

  float bias[4];
#pragma unroll
  for (int j = 0; j < 4; j++) bias[j] = bsel[h * DS + w * 64 + j * 16 + m16];
#pragma unroll
  for (int i = 0; i < 4; i++)
#pragma unroll
    for (int r = 0; r < 4; r++) {
      float s = 0.f;
#pragma unroll
      for (int j = 0; j < 4; j++) {
        acc[i][j][r] += bias[j];
        s = fmaf(acc[i][j][r], acc[i][j][r], s);
      }
      for (int off = 1; off < 16; off <<= 1) s += __shfl_xor(s, off);
      if (m16 == 0) rs[i * 16 + q * 4 + r][w] = s;
    }
  __syncthreads();

  if (z < 2) {
    float* vout = z ? voB : voA;
    if (t < 64) {
      const float ss = rs[t][0] + rs[t][1] + rs[t][2] + rs[t][3];
      if (n0 + t < NR) vout[((long)h * NR + n0 + t) * DIN] = sqrtf(1.f + ss);
    }
#pragma unroll
    for (int i = 0; i < 4; i++) {
      const int row = i * 16 + q * 4;
#pragma unroll
      for (int r = 0; r < 4; r++) {
        const int rg = n0 + row + r;
        if (rg < NR) {
          float* vo = vout + ((long)h * NR + rg) * DIN + 1 + w * 64 + m16;
          vo[0] = acc[i][0][r]; vo[16] = acc[i][1][r];
          vo[32] = acc[i][2][r]; vo[48] = acc[i][3][r];
        }
      }
    }
  } else {
    if (t < 64 && n0 + t < NR) {
      const float ss = rs[t][0] + rs[t][1] + rs[t][2] + rs[t][3];
      fr[((long)(z - 2) * HH + h) * NR + n0 + t] = 0.125f * __expf(-ss) + 1e-8f;
    }
  }
}

// ---------------------------------------------------------------------------
// feat: features = exp(sqrt(2) * (x @ WpT^T)) * front. Zero LDS.
// grid (16, 157): ch fast -> XCD L2 A-reuse; 1-deep register dbuf. (R7)
// ---------------------------------------------------------------------------
__global__ __launch_bounds__(256) void feat_kernel(
    const bf16* __restrict__ xbA, const bf16* __restrict__ xbB,
    const bf16* __restrict__ WpT, const float* __restrict__ fr,
    bf16* __restrict__ qpA, bf16* __restrict__ kpA,
    bf16* __restrict__ qpB, bf16* __restrict__ kpB)
{
  const int t = threadIdx.x;
  const int ch = blockIdx.x;
  const int h = ch & 3;
  const int c = ch >> 2;
  const int n0 = blockIdx.y * 128;
  const bf16* xb = (c >= 2) ? xbB : xbA;
  const bf16* wp = WpT + (((long)(c & 1) * HH + h) * MF) * KP;
  bf16* fout = (c == 0) ? qpA : (c == 1) ? kpA : (c == 2) ? qpB : kpB;
  const float* frc = fr + ((long)c * HH + h) * NR;
  const int w = t >> 6, lane = t & 63;
  const int m16 = lane & 15, q = lane >> 4;
  const int r0 = w * 32;

  const bf16* aptr[2];
#pragma unroll
  for (int i = 0; i < 2; i++)
    aptr[i] = xb + (long)min(n0 + r0 + i * 16 + m16, NR - 1) * KP + q * 8;
  const bf16* bptr[4];
#pragma unroll
  for (int j = 0; j < 4; j++)
    bptr[j] = wp + (long)(j * 16 + m16) * KP + q * 8;

  f32x4 acc[2][4] = {};
  bf16x8 afc[2], bfc[4], afn[2], bfn[4];
#pragma unroll
  for (int i = 0; i < 2; i++) afc[i] = *(const bf16x8*)(aptr[i]);
#pragma unroll
  for (int j = 0; j < 4; j++) bfc[j] = *(const bf16x8*)(bptr[j]);

  for (int c9 = 0; c9 < 9; c9++) {
    if (c9 < 8) {
      const int k1 = (c9 + 1) * 32;
#pragma unroll
      for (int i = 0; i < 2; i++) afn[i] = *(const bf16x8*)(aptr[i] + k1);
#pragma unroll
      for (int j = 0; j < 4; j++) bfn[j] = *(const bf16x8*)(bptr[j] + k1);
    }
#pragma unroll
    for (int i = 0; i < 2; i++)
#pragma unroll
      for (int j = 0; j < 4; j++)
        acc[i][j] = __builtin_amdgcn_mfma_f32_16x16x32_bf16(afc[i], bfc[j], acc[i][j], 0, 0, 0);
#pragma unroll
    for (int i = 0; i < 2; i++) afc[i] = afn[i];
#pragma unroll
    for (int j = 0; j < 4; j++) bfc[j] = bfn[j];
  }
  const float SQ2 = 1.41421356237309515f;
#pragma unroll
  for (int i = 0; i < 2; i++)
#pragma unroll
    for (int r = 0; r < 4; r++) {
      const int rg = n0 + r0 + i * 16 + q * 4 + r;
      if (rg < NR) {
        const float frv = frc[rg];
        bf16* fo = fout + ((long)h * NR + rg) * MF + m16;
#pragma unroll
        for (int j = 0; j < 4; j++)
          fo[j * 16] = (bf16)(__expf(SQ2 * acc[i][j][r]) * frv);
      }
    }
}

// ---------------------------------------------------------------------------
// last3: MFMA lastT[d][m] = sum_n v[n][d]*f[n][m]. grid (5, 25, 8). (unchanged)
// ---------------------------------------------------------------------------
__global__ __launch_bounds__(256) void last3_kernel(
    const float* __restrict__ vA, const bf16* __restrict__ fA,
    const float* __restrict__ vB, const bf16* __restrict__ fB,
    float* __restrict__ part)
{
  __shared__ unsigned int Va[64 * 17];
  __shared__ unsigned int Fa[64 * 17];
  const int t = threadIdx.x;
  const int dt = blockIdx.x, kc = blockIdx.y, z = blockIdx.z;
  const int side = z >> 2, h = z & 3;
  const float* v = side ? vB : vA;
  const bf16* f = side ? fB : fA;
  const int d0 = dt * 64;
  const int w = t >> 6, lane = t & 63;
  const int m16 = lane & 15, q = lane >> 4;
  const int np = t >> 4, xg = (t & 15) * 4;
  f32x4 acc[4] = {};

  for (int c = 0; c < LKC; c++) {
    const int n0 = (kc * LKC + c) * 32;
    {
      const float* s0 = v + ((long)h * NR + n0 + 2 * np) * DIN + d0 + xg;
      const float* s1 = s0 + DIN;
      if (d0 + xg + 3 < DIN) {
        const f32x4 a0 = *(const f32x4*)s0;
        const f32x4 a1 = *(const f32x4*)s1;
#pragma unroll
        for (int e = 0; e < 4; e++) {
          bf16x2 p; p[0] = (bf16)a0[e]; p[1] = (bf16)a1[e];
          Va[(xg + e) * 17 + np] = __builtin_bit_cast(unsigned int, p);
        }
      } else {
#pragma unroll
        for (int e = 0; e < 4; e++) {
          float a0 = 0.f, a1 = 0.f;
          if (d0 + xg + e < DIN) { a0 = s0[e]; a1 = s1[e]; }
          bf16x2 p; p[0] = (bf16)a0; p[1] = (bf16)a1;
          Va[(xg + e) * 17 + np] = __builtin_bit_cast(unsigned int, p);
        }
      }
    }
    {
      const bf16* s0 = f + ((long)h * NR + n0 + 2 * np) * MF + xg;
      const bf16x4 f0 = *(const bf16x4*)s0;
      const bf16x4 f1 = *(const bf16x4*)(s0 + MF);
#pragma unroll
      for (int e = 0; e < 4; e++) {
        bf16x2 p; p[0] = f0[e]; p[1] = f1[e];
        Fa[(xg + e) * 17 + np] = __builtin_bit_cast(unsigned int, p);
      }
    }
    __syncthreads();
    u32x4 bw;
#pragma unroll
    for (int c4 = 0; c4 < 4; c4++) bw[c4] = Fa[(w * 16 + m16) * 17 + q * 4 + c4];
    const bf16x8 bv = __builtin_bit_cast(bf16x8, bw);
#pragma unroll
    for (int i = 0; i < 4; i++) {
      u32x4 aw;
#pragma unroll
      for (int c4 = 0; c4 < 4; c4++) aw[c4] = Va[(i * 16 + m16) * 17 + q * 4 + c4];
      acc[i] = __builtin_amdgcn_mfma_f32_16x16x32_bf16(
          __builtin_bit_cast(bf16x8, aw), bv, acc[i], 0, 0, 0);
    }
    __syncthreads();
  }
  float* pp = part + ((long)(z * LKC + kc) * 5 + dt) * 4096;
#pragma unroll
  for (int i = 0; i < 4; i++)
#pragma unroll
    for (int r = 0; r < 4; r++)
      pp[(i * 16 + q * 4 + r) * 64 + w * 16 + m16] = acc[i][r];
}

__global__ void reduce_last4(const float* __restrict__ part,
                             bf16* __restrict__ hiU, bf16* __restrict__ loU,
                             bf16* __restrict__ hiI, bf16* __restrict__ loI) {
  const int d = blockIdx.x, zz = blockIdx.y, m = threadIdx.x;  // (272, 8) x 64
  const int side = zz >> 2, h = zz & 3;
  const int dt = d >> 6, dl = d & 63;
  float s = 0.f;
#pragma unroll 5
  for (int kc = 0; kc < LKC; kc++)
    s += part[((long)(zz * LKC + kc) * 5 + dt) * 4096 + dl * 64 + m];
  bf16* hi = side ? hiI : hiU;
  bf16* lo = side ? loI : loU;
  const bf16 hv = (bf16)s;
  hi[((long)h * LTP + d) * MF + m] = hv;
  lo[((long)h * LTP + d) * MF + m] = (bf16)(s - (float)hv);
}

// ---------------------------------------------------------------------------
// fuse3 (unchanged)
// ---------------------------------------------------------------------------
__global__ __launch_bounds__(256) void fuse3_kernel(
    const bf16* __restrict__ qpA, const float* __restrict__ vA,
    const bf16* __restrict__ hiA, const bf16* __restrict__ loA,
    const bf16* __restrict__ qpB, const float* __restrict__ vB,
    const bf16* __restrict__ hiB, const bf16* __restrict__ loB,
    float* __restrict__ out)
{
  __shared__ __align__(16) float zs[32 * ZST];

  const int side = blockIdx.y;
  const bf16* qp = side ? qpB : qpA;
  const float* v = side ? vB : vA;
  const bf16* hi = side ? hiB : hiA;
  const bf16* lo = side ? loB : loA;
  float* o = out + (long)side * NR * DIN;

  const int t = threadIdx.x;
  const int n0 = blockIdx.x * 32;
  const int w = t >> 6, lane = t & 63;
  const int m16 = lane & 15, q = lane >> 4;
  const int erow = t >> 3, ecol = (t & 7) * 4;
  const bool lead = ((t & 7) == 0);
  const int ntile = (w == 0) ? 5 : 4;

  f32x4 macc[8] = {};
  float macc256 = 0.f;

  for (int h = 0; h < HH; h++) {
    const float* vr = v + ((long)h * NR + n0 + erow) * DIN;
    f32x4 vreg[8];
#pragma unroll
    for (int it = 0; it < 8; it++)
      vreg[it] = *(const f32x4*)(vr + it * 32 + ecol);
    float v256 = lead ? vr[256] : 0.f;

    bf16x8 af[2][2];
#pragma unroll
    for (int i = 0; i < 2; i++)
#pragma unroll
      for (int hf = 0; hf < 2; hf++)
        af[i][hf] = *(const bf16x8*)(qp + ((long)h * NR + n0 + i * 16 + m16) * MF + hf * 32 + q * 8);

    for (int jt = 0; jt < ntile; jt++) {
      const int dt = (jt < 4) ? (w + jt * 4) : 16;
      const int d = dt * 16 + m16;
      const bf16* ph = hi + ((long)h * LTP + d) * MF + q * 8;
      const bf16* pl = lo + ((long)h * LTP + d) * MF + q * 8;
      const bf16x8 bh0 = *(const bf16x8*)ph, bh1 = *(const bf16x8*)(ph + 32);
      const bf16x8 bl0 = *(const bf16x8*)pl, bl1 = *(const bf16x8*)(pl + 32);
#pragma unroll
      for (int i = 0; i < 2; i++) {
        f32x4 a = {0.f, 0.f, 0.f, 0.f};
        a = __builtin_amdgcn_mfma_f32_16x16x32_bf16(af[i][1], bl1, a, 0, 0, 0);
        a = __builtin_amdgcn_mfma_f32_16x16x32_bf16(af[i][0], bl0, a, 0, 0, 0);
        a = __builtin_amdgcn_mfma_f32_16x16x32_bf16(af[i][1], bh1, a, 0, 0, 0);
        a = __builtin_amdgcn_mfma_f32_16x16x32_bf16(af[i][0], bh0, a, 0, 0, 0);
#pragma unroll
        for (int r = 0; r < 4; r++)
          zs[(i * 16 + q * 4 + r) * ZST + d] = a[r];
      }
    }
    __syncthreads();

    f32x4 zreg[8];
    float sz2 = 0.f, svz = 0.f, z0p = 0.f, v02p = 0.f;
#pragma unroll
    for (int it = 0; it < 8; it++) {
      zreg[it] = *(const f32x4*)&zs[erow * ZST + it * 32 + ecol];
#pragma unroll
      for (int c = 0; c < 4; c++) {
        sz2 = fmaf(zreg[it][c], zreg[it][c], sz2);
        svz = fmaf(vreg[it][c], zreg[it][c], svz);
      }
    }
    float z256 = 0.f;
    if (lead) {
      z256 = zs[erow * ZST + 256];
      sz2 = fmaf(z256, z256, sz2);
      svz = fmaf(v256, z256, svz);
      z0p = zreg[0][0];
      v02p = vreg[0][0] * vreg[0][0];
    }
#pragma unroll
    for (int off = 1; off < 8; off <<= 1) {
      sz2 += __shfl_xor(sz2, off);
      svz += __shfl_xor(svz, off);
      z0p += __shfl_xor(z0p, off);
      v02p += __shfl_xor(v02p, off);
    }
    const float a2 = 2.f * v02p - 1.f;
    const float mn = sz2 - 2.f * z0p * z0p;
    const float cf = 1.f / sqrtf(fabsf(mn + 1e-7f));
    const float ab = cf * svz;
    const float b2 = cf * cf * sz2;
    const float den = 1.f + 2.f * ab + a2 * b2;
    const float inv = 0.25f / (den + 1e-7f);
    const float sx = (1.f + 2.f * ab + b2) * inv;
    const float sy = (1.f - a2) * cf * inv;
#pragma unroll
    for (int it = 0; it < 8; it++)
#pragma unroll
      for (int c = 0; c < 4; c++)
        macc[it][c] = fmaf(sx, vreg[it][c], fmaf(sy, zreg[it][c], macc[it][c]));
    if (lead) macc256 = fmaf(sx, v256, fmaf(sy, z256, macc256));
    __syncthreads();
  }

  float sm2 = 0.f, m02p = 0.f;
#pragma unroll
  for (int it = 0; it < 8; it++)
#pragma unroll
    for (int c = 0; c < 4; c++) sm2 = fmaf(macc[it][c], macc[it][c], sm2);
  if (lead) {
    sm2 = fmaf(macc256, macc256, sm2);
    m02p = macc[0][0] * macc[0][0];
  }
#pragma unroll
  for (int off = 1; off < 8; off <<= 1) {
    sm2 += __shfl_xor(sm2, off);
    m02p += __shfl_xor(m02p, off);
  }
  const float fv = 1.f / sqrtf(fabsf(sm2 - 2.f * m02p) + 1e-7f);
  float* orow = o + (long)(n0 + erow) * DIN;
#pragma unroll
  for (int it = 0; it < 8; it++)
#pragma unroll
    for (int c = 0; c < 4; c++) orow[it * 32 + ecol + c] = macc[it][c] * fv;
  if (lead) orow[256] = macc256 * fv;
}

extern "C" void kernel_launch(void* const* d_in, const int* in_sizes, int n_in,
                              void* d_out, int out_size, void* d_ws, size_t ws_size,
                              hipStream_t stream) {
  const float* u    = (const float*)d_in[0];
  const float* ii   = (const float*)d_in[1];
  const float* Wk   = (const float*)d_in[2];
  const float* bk   = (const float*)d_in[3];
  const float* Wq   = (const float*)d_in[4];
  const float* bq   = (const float*)d_in[5];
  const float* Wv   = (const float*)d_in[6];
  const float* bv   = (const float*)d_in[7];
  const float* proj = (const float*)d_in[8];
  float* out = (float*)d_out;

  const long NV = (long)HH * NR * DIN;
  const long NF = (long)HH * NR * MF;
  const long NLT = (long)HH * LTP * MF;
  float* v_u = (float*)d_ws;
  float* v_i = v_u + NV;
  bf16* qp_u = (bf16*)(v_i + NV);
  bf16* kp_u = qp_u + NF;
  bf16* qp_i = kp_u + NF;
  bf16* kp_i = qp_i + NF;
  bf16* ltHi_u = kp_i + NF;
  bf16* ltLo_u = ltHi_u + NLT;
  bf16* ltHi_i = ltLo_u + NLT;
  bf16* ltLo_i = ltHi_i + NLT;
  bf16* xb_u  = ltLo_i + NLT;
  bf16* xb_i  = xb_u + (long)NR * KP;
  bf16* WbTq  = xb_i + (long)NR * KP;
  bf16* WbTk  = WbTq + 4 * 256 * KP;
  bf16* WbTv  = WbTk + 4 * 256 * KP;
  bf16* WpT   = WbTv + 4 * 256 * KP;   // 8 * 64 * KP bf16
  float* fr   = (float*)(WpT + 8 * 64 * KP);  // 16 * NR fp32
  float* part = (float*)xb_u;  // 16.4 MB split-K partials, alias xb (dead after feat)

  cvt_x_kernel<<<dim3(NR, 2), KP, 0, stream>>>(u, ii, xb_u, xb_i);
  cvt_w_kernel<<<dim3(1024, 3), KP, 0, stream>>>(Wq, Wk, Wv, WbTq, WbTk, WbTv);
  cvt_wp_kernel<<<dim3(KP, HH, 2), 64, 0, stream>>>(Wq, Wk, bq, bk, proj, WpT);

  // zh fast (24 A-sharing blocks consecutive -> XCD L2 reuse), 64-row tiles
  proj4_kernel<<<dim3(24, (NR + 63) / 64), 256, 0, stream>>>(
      xb_u, xb_i, WbTq, WbTk, WbTv, bq, bk, bv, v_u, v_i, fr);
  // ch fast (16 A-sharing blocks consecutive -> XCD L2 reuse)
  feat_kernel<<<dim3(16, (NR + 127) / 128), 256, 0, stream>>>(
      xb_u, xb_i, WpT, fr, qp_u, kp_u, qp_i, kp_i);

  // side 0 (-> lastT_u) uses (v_i, kp_i); side 1 (-> lastT_i) uses (v_u, kp_u)
  last3_kernel<<<dim3(5, LKC, 8), 256, 0, stream>>>(v_i, kp_i, v_u, kp_u, part);
  reduce_last4<<<dim3(LTP, 8), 64, 0, stream>>>(part, ltHi_u, ltLo_u, ltHi_i, ltLo_i);

  fuse3_kernel<<<dim3(NR / 32, 2), 256, 0, stream>>>(
      qp_u, v_u, ltHi_u, ltLo_u, qp_i, v_i, ltHi_i, ltLo_i, out);
}

// Round 9
// 459.927 us; speedup vs baseline: 1.0912x; 1.0912x over previous
//
#include <hip/hip_runtime.h>
#include <hip/hip_bf16.h>

#define HH 4
#define NR 20000
#define DIN 257
#define DS 256
#define MF 64
#define KP 288   // padded K for bf16 staging; k=257 is the bias-1 slot
#define VP 264   // v row stride in bf16 elems (264*2=528 B, 16B-aligned rows)
#define LTP 272  // lastT padded d-rows
#define ZST 276  // fuse3 LDS z-tile row stride
#define LKC 25   // last3 split-K: 25 grid x 25 chunks x 32 rows = 20000

typedef __bf16 bf16;
typedef bf16 bf16x8 __attribute__((ext_vector_type(8)));
typedef bf16 bf16x4 __attribute__((ext_vector_type(4)));
typedef bf16 bf16x2 __attribute__((ext_vector_type(2)));
typedef float f32x4 __attribute__((ext_vector_type(4)));
typedef unsigned int u32x4 __attribute__((ext_vector_type(4)));

// ---------------------------------------------------------------------------
// conversions
// ---------------------------------------------------------------------------
__global__ void cvt_x_kernel(const float* __restrict__ xA, const float* __restrict__ xB,
                             bf16* __restrict__ xbA, bf16* __restrict__ xbB) {
  const int n = blockIdx.x, k = threadIdx.x;  // 288 threads, y = side
  const float* x = blockIdx.y ? xB : xA;
  bf16* xb = blockIdx.y ? xbB : xbA;
  bf16 v = (bf16)0.f;
  if (k < DIN) v = (bf16)x[(long)n * DIN + k];
  else if (k == DIN) v = (bf16)1.f;  // bias-1 slot (WbT pads are 0 there)
  xb[(long)n * KP + k] = v;
}

__global__ void cvt_w_kernel(const float* __restrict__ Wq, const float* __restrict__ Wk,
                             const float* __restrict__ Wv, bf16* __restrict__ WbTq,
                             bf16* __restrict__ WbTk, bf16* __restrict__ WbTv) {
  const int which = blockIdx.y;
  const int h = blockIdx.x >> 8, n = blockIdx.x & 255, k = threadIdx.x;
  const float* W = which == 0 ? Wq : (which == 1 ? Wk : Wv);
  bf16* o = which == 0 ? WbTq : (which == 1 ? WbTk : WbTv);
  o[((long)h * 256 + n) * KP + k] =
      (k < DIN) ? (bf16)W[((long)h * DIN + k) * DS + n] : (bf16)0.f;
}

// WpT[(which*HH+h)][m][k] = sum_d W[h][k][d]*proj[d][m]; k=257 row = b.proj
__global__ void cvt_wp_kernel(const float* __restrict__ Wq, const float* __restrict__ Wk,
                              const float* __restrict__ bq, const float* __restrict__ bk,
                              const float* __restrict__ proj, bf16* __restrict__ WpT) {
  const int k = blockIdx.x, h = blockIdx.y, which = blockIdx.z, m = threadIdx.x;
  const float* W = which ? Wk : Wq;
  const float* bb = which ? bk : bq;
  float acc = 0.f;
  if (k < DIN) {
    const float* wr = W + ((long)h * DIN + k) * DS;
#pragma unroll 8
    for (int d = 0; d < DS; d++) acc = fmaf(wr[d], proj[(long)d * MF + m], acc);
  } else if (k == DIN) {
    const float* br = bb + (long)h * DS;
#pragma unroll 8
    for (int d = 0; d < DS; d++) acc = fmaf(br[d], proj[(long)d * MF + m], acc);
  }
  WpT[(((long)which * HH + h) * MF + m) * KP + k] = (bf16)acc;
}

// ---------------------------------------------------------------------------
// async global->LDS 16B helper
// ---------------------------------------------------------------------------
__device__ __forceinline__ void gl_lds16(const bf16* g, bf16* l) {
  __builtin_amdgcn_global_load_lds(
      (const __attribute__((address_space(1))) unsigned int*)g,
      (__attribute__((address_space(3))) unsigned int*)l, 16, 0, 0);
}

// ---------------------------------------------------------------------------
// proj4: LDS-staged double-buffered projection GEMM. grid (24, 313).
// R7-verified staging/sync (R8 transposed staging reverted: 0 conflicts but
// +11us -- conflicts are hidden behind the 2-phase barrier; global-side
// lane-sequential segments matter more). v output now BF16 (VP-padded rows).
// ---------------------------------------------------------------------------
__global__ __launch_bounds__(256) void proj4_kernel(
    const bf16* __restrict__ xbA, const bf16* __restrict__ xbB,
    const bf16* __restrict__ WbTq, const bf16* __restrict__ WbTk,
    const bf16* __restrict__ WbTv,
    const float* __restrict__ bq, const float* __restrict__ bk,
    const float* __restrict__ bv,
    bf16* __restrict__ voA, bf16* __restrict__ voB, float* __restrict__ fr)
{
  // 40 KB carved LDS: A dbuf [2][64*32] bf16 = 8 KB, B dbuf [2][256*32] = 32 KB.
  // rs[64][4] overlays the A buffer after the K-loop (barrier-protected).
  __shared__ __align__(16) char smem[40960];
  bf16* Ab = (bf16*)smem;              // 2 * 2048 elems
  bf16* Bb = (bf16*)(smem + 8192);     // 2 * 8192 elems
  float (*rs)[4] = (float(*)[4])smem;

  const int t = threadIdx.x;
  const int zh = blockIdx.x;
  const int h = zh & 3;
  const int z = zh >> 2;
  const int n0 = blockIdx.y * 64;
  const bf16* xb = (z == 1 || z >= 4) ? xbB : xbA;
  const bf16* WbT = (z < 2) ? WbTv : ((z == 2 || z == 4) ? WbTq : WbTk);
  const float* bsel = (z < 2) ? bv : ((z == 2 || z == 4) ? bq : bk);
  const int w = t >> 6, lane = t & 63;
  const int m16 = lane & 15, q = lane >> 4;
  const bf16* wbh = WbT + (long)h * 256 * KP;

  // staging geometry: wave w stages rows w*16..w*16+15 of each 64-row panel;
  // lane l covers row w*16+(l>>2), col (l&3)*8 (16B per lane, linear in LDS).
  const int rsub = w * 16 + (lane >> 2);
  const int cb = (lane & 3) * 8;
  const bf16* gA = xb + (long)min(n0 + rsub, NR - 1) * KP + cb;
  const bf16* gB = wbh + (long)rsub * KP + cb;

#define STAGE(buf, c)                                                        \
  do {                                                                       \
    const int _k0 = (c) * 32;                                                \
    gl_lds16(gA + _k0, Ab + (buf) * 2048 + w * 512);                         \
    _Pragma("unroll")                                                        \
    for (int e = 0; e < 4; e++)                                              \
      gl_lds16(gB + (long)e * 64 * KP + _k0,                                 \
               Bb + (buf) * 8192 + e * 2048 + w * 512);                      \
  } while (0)

  f32x4 acc[4][4] = {};
  STAGE(0, 0);

  for (int c = 0; c < 9; c++) {
    const int cur = c & 1;
    __syncthreads();  // drains vmcnt -> buf[cur] landed; all waves done with buf[1-cur]
    if (c < 8) STAGE(1 - cur, c + 1);

    bf16x8 af[4], bfj[4];
#pragma unroll
    for (int i = 0; i < 4; i++)
      af[i] = *(const bf16x8*)(Ab + cur * 2048 + (i * 16 + m16) * 32 + q * 8);
#pragma unroll
    for (int j = 0; j < 4; j++)
      bfj[j] = *(const bf16x8*)(Bb + cur * 8192 + (w * 64 + j * 16 + m16) * 32 + q * 8);
#pragma unroll
    for (int i = 0; i < 4; i++)
#pragma unroll
      for (int j = 0; j < 4; j++)
        acc[i][j] = __builtin_amdgcn_mfma_f32_16x16x32_bf16(af[i], bfj[j], acc[i][j], 0, 0, 0);
  }
#undef STAGE

  __syncthreads();  // all waves done reading Ab before rs overlays it

  float bias[4];
#pragma unroll
  for (int j = 0; j < 4; j++) bias[j] = bsel[h * DS + w * 64 + j * 16 + m16];
#pragma unroll
  for (int i = 0; i < 4; i++)
#pragma unroll
    for (int r = 0; r < 4; r++) {
      float s = 0.f;
#pragma unroll
      for (int j = 0; j < 4; j++) {
        acc[i][j][r] += bias[j];
        s = fmaf(acc[i][j][r], acc[i][j][r], s);
      }
      for (int off = 1; off < 16; off <<= 1) s += __shfl_xor(s, off);
      if (m16 == 0) rs[i * 16 + q * 4 + r][w] = s;
    }
  __syncthreads();

  if (z < 2) {
    bf16* vout = z ? voB : voA;
    if (t < 64) {
      const float ss = rs[t][0] + rs[t][1] + rs[t][2] + rs[t][3];
      if (n0 + t < NR) vout[((long)h * NR + n0 + t) * VP] = (bf16)sqrtf(1.f + ss);
    }
#pragma unroll
    for (int i = 0; i < 4; i++) {
      const int row = i * 16 + q * 4;
#pragma unroll
      for (int r = 0; r < 4; r++) {
        const int rg = n0 + row + r;
        if (rg < NR) {
          bf16* vo = vout + ((long)h * NR + rg) * VP + 1 + w * 64 + m16;
          vo[0] = (bf16)acc[i][0][r]; vo[16] = (bf16)acc[i][1][r];
          vo[32] = (bf16)acc[i][2][r]; vo[48] = (bf16)acc[i][3][r];
        }
      }
    }
  } else {
    if (t < 64 && n0 + t < NR) {
      const float ss = rs[t][0] + rs[t][1] + rs[t][2] + rs[t][3];
      fr[((long)(z - 2) * HH + h) * NR + n0 + t] = 0.125f * __expf(-ss) + 1e-8f;
    }
  }
}

// ---------------------------------------------------------------------------
// feat: features = exp(sqrt(2) * (x @ WpT^T)) * front. Zero LDS.
// grid (16, 157): ch fast -> XCD L2 A-reuse; 1-deep register dbuf. (R7)
// ---------------------------------------------------------------------------
__global__ __launch_bounds__(256) void feat_kernel(
    const bf16* __restrict__ xbA, const bf16* __restrict__ xbB,
    const bf16* __restrict__ WpT, const float* __restrict__ fr,
    bf16* __restrict__ qpA, bf16* __restrict__ kpA,
    bf16* __restrict__ qpB, bf16* __restrict__ kpB)
{
  const int t = threadIdx.x;
  const int ch = blockIdx.x;
  const int h = ch & 3;
  const int c = ch >> 2;
  const int n0 = blockIdx.y * 128;
  const bf16* xb = (c >= 2) ? xbB : xbA;
  const bf16* wp = WpT + (((long)(c & 1) * HH + h) * MF) * KP;
  bf16* fout = (c == 0) ? qpA : (c == 1) ? kpA : (c == 2) ? qpB : kpB;
  const float* frc = fr + ((long)c * HH + h) * NR;
  const int w = t >> 6, lane = t & 63;
  const int m16 = lane & 15, q = lane >> 4;
  const int r0 = w * 32;

  const bf16* aptr[2];
#pragma unroll
  for (int i = 0; i < 2; i++)
    aptr[i] = xb + (long)min(n0 + r0 + i * 16 + m16, NR - 1) * KP + q * 8;
  const bf16* bptr[4];
#pragma unroll
  for (int j = 0; j < 4; j++)
    bptr[j] = wp + (long)(j * 16 + m16) * KP + q * 8;

  f32x4 acc[2][4] = {};
  bf16x8 afc[2], bfc[4], afn[2], bfn[4];
#pragma unroll
  for (int i = 0; i < 2; i++) afc[i] = *(const bf16x8*)(aptr[i]);
#pragma unroll
  for (int j = 0; j < 4; j++) bfc[j] = *(const bf16x8*)(bptr[j]);

  for (int c9 = 0; c9 < 9; c9++) {
    if (c9 < 8) {
      const int k1 = (c9 + 1) * 32;
#pragma unroll
      for (int i = 0; i < 2; i++) afn[i] = *(const bf16x8*)(aptr[i] + k1);
#pragma unroll
      for (int j = 0; j < 4; j++) bfn[j] = *(const bf16x8*)(bptr[j] + k1);
    }
#pragma unroll
    for (int i = 0; i < 2; i++)
#pragma unroll
      for (int j = 0; j < 4; j++)
        acc[i][j] = __builtin_amdgcn_mfma_f32_16x16x32_bf16(afc[i], bfc[j], acc[i][j], 0, 0, 0);
#pragma unroll
    for (int i = 0; i < 2; i++) afc[i] = afn[i];
#pragma unroll
    for (int j = 0; j < 4; j++) bfc[j] = bfn[j];
  }
  const float SQ2 = 1.41421356237309515f;
#pragma unroll
  for (int i = 0; i < 2; i++)
#pragma unroll
    for (int r = 0; r < 4; r++) {
      const int rg = n0 + r0 + i * 16 + q * 4 + r;
      if (rg < NR) {
        const float frv = frc[rg];
        bf16* fo = fout + ((long)h * NR + rg) * MF + m16;
#pragma unroll
        for (int j = 0; j < 4; j++)
          fo[j * 16] = (bf16)(__expf(SQ2 * acc[i][j][r]) * frv);
      }
    }
}

// ---------------------------------------------------------------------------
// last3: MFMA lastT[d][m] = sum_n v[n][d]*f[n][m]. grid (5, 25, 8).
// v is now BF16 (VP-stride rows): v-staging mirrors the f-path (no cvt VALU).
// ---------------------------------------------------------------------------
__global__ __launch_bounds__(256) void last3_kernel(
    const bf16* __restrict__ vA, const bf16* __restrict__ fA,
    const bf16* __restrict__ vB, const bf16* __restrict__ fB,
    float* __restrict__ part)
{
  __shared__ unsigned int Va[64 * 17];
  __shared__ unsigned int Fa[64 * 17];
  const int t = threadIdx.x;
  const int dt = blockIdx.x, kc = blockIdx.y, z = blockIdx.z;
  const int side = z >> 2, h = z & 3;
  const bf16* v = side ? vB : vA;
  const bf16* f = side ? fB : fA;
  const int d0 = dt * 64;
  const int w = t >> 6, lane = t & 63;
  const int m16 = lane & 15, q = lane >> 4;
  const int np = t >> 4, xg = (t & 15) * 4;
  f32x4 acc[4] = {};

  for (int c = 0; c < LKC; c++) {
    const int n0 = (kc * LKC + c) * 32;
    {
      const bf16* s0 = v + ((long)h * NR + n0 + 2 * np) * VP + d0 + xg;
      const bf16* s1 = s0 + VP;
      if (d0 + xg + 3 < DIN) {
        const bf16x4 a0 = *(const bf16x4*)s0;
        const bf16x4 a1 = *(const bf16x4*)s1;
#pragma unroll
        for (int e = 0; e < 4; e++) {
          bf16x2 p; p[0] = a0[e]; p[1] = a1[e];
          Va[(xg + e) * 17 + np] = __builtin_bit_cast(unsigned int, p);
        }
      } else {
#pragma unroll
        for (int e = 0; e < 4; e++) {
          bf16 a0 = (bf16)0.f, a1 = (bf16)0.f;
          if (d0 + xg + e < DIN) { a0 = s0[e]; a1 = s1[e]; }
          bf16x2 p; p[0] = a0; p[1] = a1;
          Va[(xg + e) * 17 + np] = __builtin_bit_cast(unsigned int, p);
        }
      }
    }
    {
      const bf16* s0 = f + ((long)h * NR + n0 + 2 * np) * MF + xg;
      const bf16x4 f0 = *(const bf16x4*)s0;
      const bf16x4 f1 = *(const bf16x4*)(s0 + MF);
#pragma unroll
      for (int e = 0; e < 4; e++) {
        bf16x2 p; p[0] = f0[e]; p[1] = f1[e];
        Fa[(xg + e) * 17 + np] = __builtin_bit_cast(unsigned int, p);
      }
    }
    __syncthreads();
    u32x4 bw;
#pragma unroll
    for (int c4 = 0; c4 < 4; c4++) bw[c4] = Fa[(w * 16 + m16) * 17 + q * 4 + c4];
    const bf16x8 bv = __builtin_bit_cast(bf16x8, bw);
#pragma unroll
    for (int i = 0; i < 4; i++) {
      u32x4 aw;
#pragma unroll
      for (int c4 = 0; c4 < 4; c4++) aw[c4] = Va[(i * 16 + m16) * 17 + q * 4 + c4];
      acc[i] = __builtin_amdgcn_mfma_f32_16x16x32_bf16(
          __builtin_bit_cast(bf16x8, aw), bv, acc[i], 0, 0, 0);
    }
    __syncthreads();
  }
  float* pp = part + ((long)(z * LKC + kc) * 5 + dt) * 4096;
#pragma unroll
  for (int i = 0; i < 4; i++)
#pragma unroll
    for (int r = 0; r < 4; r++)
      pp[(i * 16 + q * 4 + r) * 64 + w * 16 + m16] = acc[i][r];
}

__global__ void reduce_last4(const float* __restrict__ part,
                             bf16* __restrict__ hiU, bf16* __restrict__ loU,
                             bf16* __restrict__ hiI, bf16* __restrict__ loI) {
  const int d = blockIdx.x, zz = blockIdx.y, m = threadIdx.x;  // (272, 8) x 64
  const int side = zz >> 2, h = zz & 3;
  const int dt = d >> 6, dl = d & 63;
  float s = 0.f;
#pragma unroll 5
  for (int kc = 0; kc < LKC; kc++)
    s += part[((long)(zz * LKC + kc) * 5 + dt) * 4096 + dl * 64 + m];
  bf16* hi = side ? hiI : hiU;
  bf16* lo = side ? loI : loU;
  const bf16 hv = (bf16)s;
  hi[((long)h * LTP + d) * MF + m] = hv;
  lo[((long)h * LTP + d) * MF + m] = (bf16)(s - (float)hv);
}

// ---------------------------------------------------------------------------
// fuse3: v is now BF16 (VP-stride rows); vreg converted bf16->f32 on load.
// ---------------------------------------------------------------------------
__global__ __launch_bounds__(256) void fuse3_kernel(
    const bf16* __restrict__ qpA, const bf16* __restrict__ vA,
    const bf16* __restrict__ hiA, const bf16* __restrict__ loA,
    const bf16* __restrict__ qpB, const bf16* __restrict__ vB,
    const bf16* __restrict__ hiB, const bf16* __restrict__ loB,
    float* __restrict__ out)
{
  __shared__ __align__(16) float zs[32 * ZST];

  const int side = blockIdx.y;
  const bf16* qp = side ? qpB : qpA;
  const bf16* v = side ? vB : vA;
  const bf16* hi = side ? hiB : hiA;
  const bf16* lo = side ? loB : loA;
  float* o = out + (long)side * NR * DIN;

  const int t = threadIdx.x;
  const int n0 = blockIdx.x * 32;
  const int w = t >> 6, lane = t & 63;
  const int m16 = lane & 15, q = lane >> 4;
  const int erow = t >> 3, ecol = (t & 7) * 4;
  const bool lead = ((t & 7) == 0);
  const int ntile = (w == 0) ? 5 : 4;

  f32x4 macc[8] = {};
  float macc256 = 0.f;

  for (int h = 0; h < HH; h++) {
    const bf16* vr = v + ((long)h * NR + n0 + erow) * VP;
    f32x4 vreg[8];
#pragma unroll
    for (int it = 0; it < 8; it++) {
      const bf16x4 vb = *(const bf16x4*)(vr + it * 32 + ecol);
#pragma unroll
      for (int c = 0; c < 4; c++) vreg[it][c] = (float)vb[c];
    }
    float v256 = lead ? (float)vr[256] : 0.f;

    bf16x8 af[2][2];
#pragma unroll
    for (int i = 0; i < 2; i++)
#pragma unroll
      for (int hf = 0; hf < 2; hf++)
        af[i][hf] = *(const bf16x8*)(qp + ((long)h * NR + n0 + i * 16 + m16) * MF + hf * 32 + q * 8);

    for (int jt = 0; jt < ntile; jt++) {
      const int dt = (jt < 4) ? (w + jt * 4) : 16;
      const int d = dt * 16 + m16;
      const bf16* ph = hi + ((long)h * LTP + d) * MF + q * 8;
      const bf16* pl = lo + ((long)h * LTP + d) * MF + q * 8;
      const bf16x8 bh0 = *(const bf16x8*)ph, bh1 = *(const bf16x8*)(ph + 32);
      const bf16x8 bl0 = *(const bf16x8*)pl, bl1 = *(const bf16x8*)(pl + 32);
#pragma unroll
      for (int i = 0; i < 2; i++) {
        f32x4 a = {0.f, 0.f, 0.f, 0.f};
        a = __builtin_amdgcn_mfma_f32_16x16x32_bf16(af[i][1], bl1, a, 0, 0, 0);
        a = __builtin_amdgcn_mfma_f32_16x16x32_bf16(af[i][0], bl0, a, 0, 0, 0);
        a = __builtin_amdgcn_mfma_f32_16x16x32_bf16(af[i][1], bh1, a, 0, 0, 0);
        a = __builtin_amdgcn_mfma_f32_16x16x32_bf16(af[i][0], bh0, a, 0, 0, 0);
#pragma unroll
        for (int r = 0; r < 4; r++)
          zs[(i * 16 + q * 4 + r) * ZST + d] = a[r];
      }
    }
    __syncthreads();

    f32x4 zreg[8];
    float sz2 = 0.f, svz = 0.f, z0p = 0.f, v02p = 0.f;
#pragma unroll
    for (int it = 0; it < 8; it++) {
      zreg[it] = *(const f32x4*)&zs[erow * ZST + it * 32 + ecol];
#pragma unroll
      for (int c = 0; c < 4; c++) {
        sz2 = fmaf(zreg[it][c], zreg[it][c], sz2);
        svz = fmaf(vreg[it][c], zreg[it][c], svz);
      }
    }
    float z256 = 0.f;
    if (lead) {
      z256 = zs[erow * ZST + 256];
      sz2 = fmaf(z256, z256, sz2);
      svz = fmaf(v256, z256, svz);
      z0p = zreg[0][0];
      v02p = vreg[0][0] * vreg[0][0];
    }
#pragma unroll
    for (int off = 1; off < 8; off <<= 1) {
      sz2 += __shfl_xor(sz2, off);
      svz += __shfl_xor(svz, off);
      z0p += __shfl_xor(z0p, off);
      v02p += __shfl_xor(v02p, off);
    }
    const float a2 = 2.f * v02p - 1.f;
    const float mn = sz2 - 2.f * z0p * z0p;
    const float cf = 1.f / sqrtf(fabsf(mn + 1e-7f));
    const float ab = cf * svz;
    const float b2 = cf * cf * sz2;
    const float den = 1.f + 2.f * ab + a2 * b2;
    const float inv = 0.25f / (den + 1e-7f);
    const float sx = (1.f + 2.f * ab + b2) * inv;
    const float sy = (1.f - a2) * cf * inv;
#pragma unroll
    for (int it = 0; it < 8; it++)
#pragma unroll
      for (int c = 0; c < 4; c++)
        macc[it][c] = fmaf(sx, vreg[it][c], fmaf(sy, zreg[it][c], macc[it][c]));
    if (lead) macc256 = fmaf(sx, v256, fmaf(sy, z256, macc256));
    __syncthreads();
  }

  float sm2 = 0.f, m02p = 0.f;
#pragma unroll
  for (int it = 0; it < 8; it++)
#pragma unroll
    for (int c = 0; c < 4; c++) sm2 = fmaf(macc[it][c], macc[it][c], sm2);
  if (lead) {
    sm2 = fmaf(macc256, macc256, sm2);
    m02p = macc[0][0] * macc[0][0];
  }
#pragma unroll
  for (int off = 1; off < 8; off <<= 1) {
    sm2 += __shfl_xor(sm2, off);
    m02p += __shfl_xor(m02p, off);
  }
  const float fv = 1.f / sqrtf(fabsf(sm2 - 2.f * m02p) + 1e-7f);
  float* orow = o + (long)(n0 + erow) * DIN;
#pragma unroll
  for (int it = 0; it < 8; it++)
#pragma unroll
    for (int c = 0; c < 4; c++) orow[it * 32 + ecol + c] = macc[it][c] * fv;
  if (lead) orow[256] = macc256 * fv;
}

extern "C" void kernel_launch(void* const* d_in, const int* in_sizes, int n_in,
                              void* d_out, int out_size, void* d_ws, size_t ws_size,
                              hipStream_t stream) {
  const float* u    = (const float*)d_in[0];
  const float* ii   = (const float*)d_in[1];
  const float* Wk   = (const float*)d_in[2];
  const float* bk   = (const float*)d_in[3];
  const float* Wq   = (const float*)d_in[4];
  const float* bq   = (const float*)d_in[5];
  const float* Wv   = (const float*)d_in[6];
  const float* bv   = (const float*)d_in[7];
  const float* proj = (const float*)d_in[8];
  float* out = (float*)d_out;

  const long NVB = (long)HH * NR * VP;   // v in bf16, VP-padded rows
  const long NF = (long)HH * NR * MF;
  const long NLT = (long)HH * LTP * MF;
  bf16* v_u = (bf16*)d_ws;
  bf16* v_i = v_u + NVB;
  bf16* qp_u = v_i + NVB;
  bf16* kp_u = qp_u + NF;
  bf16* qp_i = kp_u + NF;
  bf16* kp_i = qp_i + NF;
  bf16* ltHi_u = kp_i + NF;
  bf16* ltLo_u = ltHi_u + NLT;
  bf16* ltHi_i = ltLo_u + NLT;
  bf16* ltLo_i = ltHi_i + NLT;
  bf16* xb_u  = ltLo_i + NLT;
  bf16* xb_i  = xb_u + (long)NR * KP;
  bf16* WbTq  = xb_i + (long)NR * KP;
  bf16* WbTk  = WbTq + 4 * 256 * KP;
  bf16* WbTv  = WbTk + 4 * 256 * KP;
  bf16* WpT   = WbTv + 4 * 256 * KP;   // 8 * 64 * KP bf16
  float* fr   = (float*)(WpT + 8 * 64 * KP);  // 16 * NR fp32
  float* part = (float*)xb_u;  // 16.4 MB split-K partials, alias xb (dead after feat)

  cvt_x_kernel<<<dim3(NR, 2), KP, 0, stream>>>(u, ii, xb_u, xb_i);
  cvt_w_kernel<<<dim3(1024, 3), KP, 0, stream>>>(Wq, Wk, Wv, WbTq, WbTk, WbTv);
  cvt_wp_kernel<<<dim3(KP, HH, 2), 64, 0, stream>>>(Wq, Wk, bq, bk, proj, WpT);

  // zh fast (24 A-sharing blocks consecutive -> XCD L2 reuse), 64-row tiles
  proj4_kernel<<<dim3(24, (NR + 63) / 64), 256, 0, stream>>>(
      xb_u, xb_i, WbTq, WbTk, WbTv, bq, bk, bv, v_u, v_i, fr);
  // ch fast (16 A-sharing blocks consecutive -> XCD L2 reuse)
  feat_kernel<<<dim3(16, (NR + 127) / 128), 256, 0, stream>>>(
      xb_u, xb_i, WpT, fr, qp_u, kp_u, qp_i, kp_i);

  // side 0 (-> lastT_u) uses (v_i, kp_i); side 1 (-> lastT_i) uses (v_u, kp_u)
  last3_kernel<<<dim3(5, LKC, 8), 256, 0, stream>>>(v_i, kp_i, v_u, kp_u, part);
  reduce_last4<<<dim3(LTP, 8), 64, 0, stream>>>(part, ltHi_u, ltLo_u, ltHi_i, ltLo_i);

  fuse3_kernel<<<dim3(NR / 32, 2), 256, 0, stream>>>(
      qp_u, v_u, ltHi_u, ltLo_u, qp_i, v_i, ltHi_i, ltLo_i, out);
}

// Round 10
// 439.124 us; speedup vs baseline: 1.1429x; 1.0474x over previous
//
#include <hip/hip_runtime.h>
#include <hip/hip_bf16.h>

#define HH 4
#define NR 20000
#define DIN 257
#define DS 256
#define MF 64
#define KP 288   // padded K for bf16 staging; k=257 is the bias-1 slot
#define VP 264   // v row stride in bf16 elems (264*2=528 B, 16B-aligned rows)
#define LTP 272  // lastT padded d-rows
#define ZST 276  // fuse3 LDS z-tile row stride
#define LKC 25   // last3 split-K: 25 grid x 25 chunks x 32 rows = 20000

typedef __bf16 bf16;
typedef bf16 bf16x8 __attribute__((ext_vector_type(8)));
typedef bf16 bf16x4 __attribute__((ext_vector_type(4)));
typedef bf16 bf16x2 __attribute__((ext_vector_type(2)));
typedef float f32x4 __attribute__((ext_vector_type(4)));
typedef unsigned int u32x4 __attribute__((ext_vector_type(4)));

// ---------------------------------------------------------------------------
// conversions
// ---------------------------------------------------------------------------
__global__ void cvt_x_kernel(const float* __restrict__ xA, const float* __restrict__ xB,
                             bf16* __restrict__ xbA, bf16* __restrict__ xbB) {
  const int n = blockIdx.x, k = threadIdx.x;  // 288 threads, y = side
  const float* x = blockIdx.y ? xB : xA;
  bf16* xb = blockIdx.y ? xbB : xbA;
  bf16 v = (bf16)0.f;
  if (k < DIN) v = (bf16)x[(long)n * DIN + k];
  else if (k == DIN) v = (bf16)1.f;  // bias-1 slot (WbT pads are 0 there)
  xb[(long)n * KP + k] = v;
}

__global__ void cvt_w_kernel(const float* __restrict__ Wq, const float* __restrict__ Wk,
                             const float* __restrict__ Wv, bf16* __restrict__ WbTq,
                             bf16* __restrict__ WbTk, bf16* __restrict__ WbTv) {
  const int which = blockIdx.y;
  const int h = blockIdx.x >> 8, n = blockIdx.x & 255, k = threadIdx.x;
  const float* W = which == 0 ? Wq : (which == 1 ? Wk : Wv);
  bf16* o = which == 0 ? WbTq : (which == 1 ? WbTk : WbTv);
  o[((long)h * 256 + n) * KP + k] =
      (k < DIN) ? (bf16)W[((long)h * DIN + k) * DS + n] : (bf16)0.f;
}

// WpT[(which*HH+h)][m][k] = sum_d W[h][k][d]*proj[d][m]; k=257 row = b.proj
__global__ void cvt_wp_kernel(const float* __restrict__ Wq, const float* __restrict__ Wk,
                              const float* __restrict__ bq, const float* __restrict__ bk,
                              const float* __restrict__ proj, bf16* __restrict__ WpT) {
  const int k = blockIdx.x, h = blockIdx.y, which = blockIdx.z, m = threadIdx.x;
  const float* W = which ? Wk : Wq;
  const float* bb = which ? bk : bq;
  float acc = 0.f;
  if (k < DIN) {
    const float* wr = W + ((long)h * DIN + k) * DS;
#pragma unroll 8
    for (int d = 0; d < DS; d++) acc = fmaf(wr[d], proj[(long)d * MF + m], acc);
  } else if (k == DIN) {
    const float* br = bb + (long)h * DS;
#pragma unroll 8
    for (int d = 0; d < DS; d++) acc = fmaf(br[d], proj[(long)d * MF + m], acc);
  }
  WpT[(((long)which * HH + h) * MF + m) * KP + k] = (bf16)acc;
}

// ---------------------------------------------------------------------------
// async global->LDS 16B helper
// ---------------------------------------------------------------------------
__device__ __forceinline__ void gl_lds16(const bf16* g, bf16* l) {
  __builtin_amdgcn_global_load_lds(
      (const __attribute__((address_space(1))) unsigned int*)g,
      (__attribute__((address_space(3))) unsigned int*)l, 16, 0, 0);
}

// ---------------------------------------------------------------------------
// proj4+feat fused: LDS-staged double-buffered projection GEMM. grid (24, 313).
// blockIdx.x = zh (z*4+h, FAST dim -> A-tile L2 reuse across the 8 XCDs).
// z: 0=value-u 1=value-i 2=q-u 3=k-u 4=q-i 5=k-i
// Block = 64 rows x 256 cols, 4 waves, acc 4x4; R7-verified 2-barrier sync.
// NEW (R10): z>=2 blocks also compute the feat output (x @ WpT slice, 64
// cols; wave w owns WpT cols w*16..w*16+15 via direct-global B-frags, +4
// MFMA/chunk into acc5) and consume their own row-norms as fr from LDS --
// the standalone feat kernel and the global fr array are eliminated.
// ---------------------------------------------------------------------------
__global__ __launch_bounds__(256) void proj4_kernel(
    const bf16* __restrict__ xbA, const bf16* __restrict__ xbB,
    const bf16* __restrict__ WbTq, const bf16* __restrict__ WbTk,
    const bf16* __restrict__ WbTv, const bf16* __restrict__ WpT,
    const float* __restrict__ bq, const float* __restrict__ bk,
    const float* __restrict__ bv,
    bf16* __restrict__ voA, bf16* __restrict__ voB,
    bf16* __restrict__ qpA, bf16* __restrict__ kpA,
    bf16* __restrict__ qpB, bf16* __restrict__ kpB)
{
  // 40 KB carved LDS: A dbuf [2][64*32] bf16 = 8 KB, B dbuf [2][256*32] = 32 KB.
  // rs[64][4] (smem+0) and frl[64] (smem+2048) overlay the A buffers after
  // the K-loop (barrier-protected).
  __shared__ __align__(16) char smem[40960];
  bf16* Ab = (bf16*)smem;              // 2 * 2048 elems
  bf16* Bb = (bf16*)(smem + 8192);     // 2 * 8192 elems
  float (*rs)[4] = (float(*)[4])smem;
  float* frl = (float*)(smem + 2048);

  const int t = threadIdx.x;
  const int zh = blockIdx.x;
  const int h = zh & 3;
  const int z = zh >> 2;
  const int n0 = blockIdx.y * 64;
  const bf16* xb = (z == 1 || z >= 4) ? xbB : xbA;
  const bf16* WbT = (z < 2) ? WbTv : ((z == 2 || z == 4) ? WbTq : WbTk);
  const float* bsel = (z < 2) ? bv : ((z == 2 || z == 4) ? bq : bk);
  const int w = t >> 6, lane = t & 63;
  const int m16 = lane & 15, q = lane >> 4;
  const bf16* wbh = WbT + (long)h * 256 * KP;

  // staging geometry: wave w stages rows w*16..w*16+15 of each 64-row panel;
  // lane l covers row w*16+(l>>2), col (l&3)*8 (16B per lane, linear in LDS).
  const int rsub = w * 16 + (lane >> 2);
  const int cb = (lane & 3) * 8;
  const bf16* gA = xb + (long)min(n0 + rsub, NR - 1) * KP + cb;
  const bf16* gB = wbh + (long)rsub * KP + cb;

  // feat B-operand (z>=2): wave w owns WpT cols w*16..w*16+15.
  const int which = (z == 2 || z == 4) ? 0 : 1;
  const bf16* gWp = WpT + (((long)which * HH + h) * MF + (w * 16 + m16)) * KP + q * 8;

#define STAGE(buf, c)                                                        \
  do {                                                                       \
    const int _k0 = (c) * 32;                                                \
    gl_lds16(gA + _k0, Ab + (buf) * 2048 + w * 512);                         \
    _Pragma("unroll")                                                        \
    for (int e = 0; e < 4; e++)                                              \
      gl_lds16(gB + (long)e * 64 * KP + _k0,                                 \
               Bb + (buf) * 8192 + e * 2048 + w * 512);                      \
  } while (0)

  f32x4 acc[4][4] = {};
  f32x4 acc5[4] = {};
  STAGE(0, 0);

  for (int c = 0; c < 9; c++) {
    const int cur = c & 1;
    __syncthreads();  // drains vmcnt -> buf[cur] landed; all waves done with buf[1-cur]
    if (c < 8) STAGE(1 - cur, c + 1);

    bf16x8 af[4], bfj[4];
#pragma unroll
    for (int i = 0; i < 4; i++)
      af[i] = *(const bf16x8*)(Ab + cur * 2048 + (i * 16 + m16) * 32 + q * 8);
#pragma unroll
    for (int j = 0; j < 4; j++)
      bfj[j] = *(const bf16x8*)(Bb + cur * 8192 + (w * 64 + j * 16 + m16) * 32 + q * 8);
#pragma unroll
    for (int i = 0; i < 4; i++)
#pragma unroll
      for (int j = 0; j < 4; j++)
        acc[i][j] = __builtin_amdgcn_mfma_f32_16x16x32_bf16(af[i], bfj[j], acc[i][j], 0, 0, 0);
    if (z >= 2) {
      const bf16x8 bf5 = *(const bf16x8*)(gWp + c * 32);
#pragma unroll
      for (int i = 0; i < 4; i++)
        acc5[i] = __builtin_amdgcn_mfma_f32_16x16x32_bf16(af[i], bf5, acc5[i], 0, 0, 0);
    }
  }
#undef STAGE

  __syncthreads();  // all waves done reading Ab before rs/frl overlay it

  float bias[4];
#pragma unroll
  for (int j = 0; j < 4; j++) bias[j] = bsel[h * DS + w * 64 + j * 16 + m16];
#pragma unroll
  for (int i = 0; i < 4; i++)
#pragma unroll
    for (int r = 0; r < 4; r++) {
      float s = 0.f;
#pragma unroll
      for (int j = 0; j < 4; j++) {
        acc[i][j][r] += bias[j];
        s = fmaf(acc[i][j][r], acc[i][j][r], s);
      }
      for (int off = 1; off < 16; off <<= 1) s += __shfl_xor(s, off);
      if (m16 == 0) rs[i * 16 + q * 4 + r][w] = s;
    }
  __syncthreads();

  if (z < 2) {
    bf16* vout = z ? voB : voA;
    if (t < 64) {
      const float ss = rs[t][0] + rs[t][1] + rs[t][2] + rs[t][3];
      if (n0 + t < NR) vout[((long)h * NR + n0 + t) * VP] = (bf16)sqrtf(1.f + ss);
    }
#pragma unroll
    for (int i = 0; i < 4; i++) {
      const int row = i * 16 + q * 4;
#pragma unroll
      for (int r = 0; r < 4; r++) {
        const int rg = n0 + row + r;
        if (rg < NR) {
          bf16* vo = vout + ((long)h * NR + rg) * VP + 1 + w * 64 + m16;
          vo[0] = (bf16)acc[i][0][r]; vo[16] = (bf16)acc[i][1][r];
          vo[32] = (bf16)acc[i][2][r]; vo[48] = (bf16)acc[i][3][r];
        }
      }
    }
  } else {
    // fr into LDS (row-norm front factor), then feat output from acc5.
    if (t < 64) {
      const float ss = rs[t][0] + rs[t][1] + rs[t][2] + rs[t][3];
      frl[t] = 0.125f * __expf(-ss) + 1e-8f;
    }
    __syncthreads();
    bf16* fout = (z == 2) ? qpA : (z == 3) ? kpA : (z == 4) ? qpB : kpB;
    const float SQ2 = 1.41421356237309515f;
#pragma unroll
    for (int i = 0; i < 4; i++) {
      const int row = i * 16 + q * 4;
#pragma unroll
      for (int r = 0; r < 4; r++) {
        const int rg = n0 + row + r;
        if (rg < NR) {
          const float frv = frl[row + r];
          fout[((long)h * NR + rg) * MF + w * 16 + m16] =
              (bf16)(__expf(SQ2 * acc5[i][r]) * frv);
        }
      }
    }
  }
}

// ---------------------------------------------------------------------------
// last3: MFMA lastT[d][m] = sum_n v[n][d]*f[n][m]. grid (5, 25, 8).
// v is BF16 (VP-stride rows): v-staging mirrors the f-path (no cvt VALU).
// ---------------------------------------------------------------------------
__global__ __launch_bounds__(256) void last3_kernel(
    const bf16* __restrict__ vA, const bf16* __restrict__ fA,
    const bf16* __restrict__ vB, const bf16* __restrict__ fB,
    float* __restrict__ part)
{
  __shared__ unsigned int Va[64 * 17];
  __shared__ unsigned int Fa[64 * 17];
  const int t = threadIdx.x;
  const int dt = blockIdx.x, kc = blockIdx.y, z = blockIdx.z;
  const int side = z >> 2, h = z & 3;
  const bf16* v = side ? vB : vA;
  const bf16* f = side ? fB : fA;
  const int d0 = dt * 64;
  const int w = t >> 6, lane = t & 63;
  const int m16 = lane & 15, q = lane >> 4;
  const int np = t >> 4, xg = (t & 15) * 4;
  f32x4 acc[4] = {};

  for (int c = 0; c < LKC; c++) {
    const int n0 = (kc * LKC + c) * 32;
    {
      const bf16* s0 = v + ((long)h * NR + n0 + 2 * np) * VP + d0 + xg;
      const bf16* s1 = s0 + VP;
      if (d0 + xg + 3 < DIN) {
        const bf16x4 a0 = *(const bf16x4*)s0;
        const bf16x4 a1 = *(const bf16x4*)s1;
#pragma unroll
        for (int e = 0; e < 4; e++) {
          bf16x2 p; p[0] = a0[e]; p[1] = a1[e];
          Va[(xg + e) * 17 + np] = __builtin_bit_cast(unsigned int, p);
        }
      } else {
#pragma unroll
        for (int e = 0; e < 4; e++) {
          bf16 a0 = (bf16)0.f, a1 = (bf16)0.f;
          if (d0 + xg + e < DIN) { a0 = s0[e]; a1 = s1[e]; }
          bf16x2 p; p[0] = a0; p[1] = a1;
          Va[(xg + e) * 17 + np] = __builtin_bit_cast(unsigned int, p);
        }
      }
    }
    {
      const bf16* s0 = f + ((long)h * NR + n0 + 2 * np) * MF + xg;
      const bf16x4 f0 = *(const bf16x4*)s0;
      const bf16x4 f1 = *(const bf16x4*)(s0 + MF);
#pragma unroll
      for (int e = 0; e < 4; e++) {
        bf16x2 p; p[0] = f0[e]; p[1] = f1[e];
        Fa[(xg + e) * 17 + np] = __builtin_bit_cast(unsigned int, p);
      }
    }
    __syncthreads();
    u32x4 bw;
#pragma unroll
    for (int c4 = 0; c4 < 4; c4++) bw[c4] = Fa[(w * 16 + m16) * 17 + q * 4 + c4];
    const bf16x8 bv = __builtin_bit_cast(bf16x8, bw);
#pragma unroll
    for (int i = 0; i < 4; i++) {
      u32x4 aw;
#pragma unroll
      for (int c4 = 0; c4 < 4; c4++) aw[c4] = Va[(i * 16 + m16) * 17 + q * 4 + c4];
      acc[i] = __builtin_amdgcn_mfma_f32_16x16x32_bf16(
          __builtin_bit_cast(bf16x8, aw), bv, acc[i], 0, 0, 0);
    }
    __syncthreads();
  }
  float* pp = part + ((long)(z * LKC + kc) * 5 + dt) * 4096;
#pragma unroll
  for (int i = 0; i < 4; i++)
#pragma unroll
    for (int r = 0; r < 4; r++)
      pp[(i * 16 + q * 4 + r) * 64 + w * 16 + m16] = acc[i][r];
}

__global__ void reduce_last4(const float* __restrict__ part,
                             bf16* __restrict__ hiU, bf16* __restrict__ loU,
                             bf16* __restrict__ hiI, bf16* __restrict__ loI) {
  const int d = blockIdx.x, zz = blockIdx.y, m = threadIdx.x;  // (272, 8) x 64
  const int side = zz >> 2, h = zz & 3;
  const int dt = d >> 6, dl = d & 63;
  float s = 0.f;
#pragma unroll 5
  for (int kc = 0; kc < LKC; kc++)
    s += part[((long)(zz * LKC + kc) * 5 + dt) * 4096 + dl * 64 + m];
  bf16* hi = side ? hiI : hiU;
  bf16* lo = side ? loI : loU;
  const bf16 hv = (bf16)s;
  hi[((long)h * LTP + d) * MF + m] = hv;
  lo[((long)h * LTP + d) * MF + m] = (bf16)(s - (float)hv);
}

// ---------------------------------------------------------------------------
// fuse3: v is BF16 (VP-stride rows); vreg converted bf16->f32 on load.
// ---------------------------------------------------------------------------
__global__ __launch_bounds__(256) void fuse3_kernel(
    const bf16* __restrict__ qpA, const bf16* __restrict__ vA,
    const bf16* __restrict__ hiA, const bf16* __restrict__ loA,
    const bf16* __restrict__ qpB, const bf16* __restrict__ vB,
    const bf16* __restrict__ hiB, const bf16* __restrict__ loB,
    float* __restrict__ out)
{
  __shared__ __align__(16) float zs[32 * ZST];

  const int side = blockIdx.y;
  const bf16* qp = side ? qpB : qpA;
  const bf16* v = side ? vB : vA;
  const bf16* hi = side ? hiB : hiA;
  const bf16* lo = side ? loB : loA;
  float* o = out + (long)side * NR * DIN;

  const int t = threadIdx.x;
  const int n0 = blockIdx.x * 32;
  const int w = t >> 6, lane = t & 63;
  const int m16 = lane & 15, q = lane >> 4;
  const int erow = t >> 3, ecol = (t & 7) * 4;
  const bool lead = ((t & 7) == 0);
  const int ntile = (w == 0) ? 5 : 4;

  f32x4 macc[8] = {};
  float macc256 = 0.f;

  for (int h = 0; h < HH; h++) {
    const bf16* vr = v + ((long)h * NR + n0 + erow) * VP;
    f32x4 vreg[8];
#pragma unroll
    for (int it = 0; it < 8; it++) {
      const bf16x4 vb = *(const bf16x4*)(vr + it * 32 + ecol);
#pragma unroll
      for (int c = 0; c < 4; c++) vreg[it][c] = (float)vb[c];
    }
    float v256 = lead ? (float)vr[256] : 0.f;

    bf16x8 af[2][2];
#pragma unroll
    for (int i = 0; i < 2; i++)
#pragma unroll
      for (int hf = 0; hf < 2; hf++)
        af[i][hf] = *(const bf16x8*)(qp + ((long)h * NR + n0 + i * 16 + m16) * MF + hf * 32 + q * 8);

    for (int jt = 0; jt < ntile; jt++) {
      const int dt = (jt < 4) ? (w + jt * 4) : 16;
      const int d = dt * 16 + m16;
      const bf16* ph = hi + ((long)h * LTP + d) * MF + q * 8;
      const bf16* pl = lo + ((long)h * LTP + d) * MF + q * 8;
      const bf16x8 bh0 = *(const bf16x8*)ph, bh1 = *(const bf16x8*)(ph + 32);
      const bf16x8 bl0 = *(const bf16x8*)pl, bl1 = *(const bf16x8*)(pl + 32);
#pragma unroll
      for (int i = 0; i < 2; i++) {
        f32x4 a = {0.f, 0.f, 0.f, 0.f};
        a = __builtin_amdgcn_mfma_f32_16x16x32_bf16(af[i][1], bl1, a, 0, 0, 0);
        a = __builtin_amdgcn_mfma_f32_16x16x32_bf16(af[i][0], bl0, a, 0, 0, 0);
        a = __builtin_amdgcn_mfma_f32_16x16x32_bf16(af[i][1], bh1, a, 0, 0, 0);
        a = __builtin_amdgcn_mfma_f32_16x16x32_bf16(af[i][0], bh0, a, 0, 0, 0);
#pragma unroll
        for (int r = 0; r < 4; r++)
          zs[(i * 16 + q * 4 + r) * ZST + d] = a[r];
      }
    }
    __syncthreads();

    f32x4 zreg[8];
    float sz2 = 0.f, svz = 0.f, z0p = 0.f, v02p = 0.f;
#pragma unroll
    for (int it = 0; it < 8; it++) {
      zreg[it] = *(const f32x4*)&zs[erow * ZST + it * 32 + ecol];
#pragma unroll
      for (int c = 0; c < 4; c++) {
        sz2 = fmaf(zreg[it][c], zreg[it][c], sz2);
        svz = fmaf(vreg[it][c], zreg[it][c], svz);
      }
    }
    float z256 = 0.f;
    if (lead) {
      z256 = zs[erow * ZST + 256];
      sz2 = fmaf(z256, z256, sz2);
      svz = fmaf(v256, z256, svz);
      z0p = zreg[0][0];
      v02p = vreg[0][0] * vreg[0][0];
    }
#pragma unroll
    for (int off = 1; off < 8; off <<= 1) {
      sz2 += __shfl_xor(sz2, off);
      svz += __shfl_xor(svz, off);
      z0p += __shfl_xor(z0p, off);
      v02p += __shfl_xor(v02p, off);
    }
    const float a2 = 2.f * v02p - 1.f;
    const float mn = sz2 - 2.f * z0p * z0p;
    const float cf = 1.f / sqrtf(fabsf(mn + 1e-7f));
    const float ab = cf * svz;
    const float b2 = cf * cf * sz2;
    const float den = 1.f + 2.f * ab + a2 * b2;
    const float inv = 0.25f / (den + 1e-7f);
    const float sx = (1.f + 2.f * ab + b2) * inv;
    const float sy = (1.f - a2) * cf * inv;
#pragma unroll
    for (int it = 0; it < 8; it++)
#pragma unroll
      for (int c = 0; c < 4; c++)
        macc[it][c] = fmaf(sx, vreg[it][c], fmaf(sy, zreg[it][c], macc[it][c]));
    if (lead) macc256 = fmaf(sx, v256, fmaf(sy, z256, macc256));
    __syncthreads();
  }

  float sm2 = 0.f, m02p = 0.f;
#pragma unroll
  for (int it = 0; it < 8; it++)
#pragma unroll
    for (int c = 0; c < 4; c++) sm2 = fmaf(macc[it][c], macc[it][c], sm2);
  if (lead) {
    sm2 = fmaf(macc256, macc256, sm2);
    m02p = macc[0][0] * macc[0][0];
  }
#pragma unroll
  for (int off = 1; off < 8; off <<= 1) {
    sm2 += __shfl_xor(sm2, off);
    m02p += __shfl_xor(m02p, off);
  }
  const float fv = 1.f / sqrtf(fabsf(sm2 - 2.f * m02p) + 1e-7f);
  float* orow = o + (long)(n0 + erow) * DIN;
#pragma unroll
  for (int it = 0; it < 8; it++)
#pragma unroll
    for (int c = 0; c < 4; c++) orow[it * 32 + ecol + c] = macc[it][c] * fv;
  if (lead) orow[256] = macc256 * fv;
}

extern "C" void kernel_launch(void* const* d_in, const int* in_sizes, int n_in,
                              void* d_out, int out_size, void* d_ws, size_t ws_size,
                              hipStream_t stream) {
  const float* u    = (const float*)d_in[0];
  const float* ii   = (const float*)d_in[1];
  const float* Wk   = (const float*)d_in[2];
  const float* bk   = (const float*)d_in[3];
  const float* Wq   = (const float*)d_in[4];
  const float* bq   = (const float*)d_in[5];
  const float* Wv   = (const float*)d_in[6];
  const float* bv   = (const float*)d_in[7];
  const float* proj = (const float*)d_in[8];
  float* out = (float*)d_out;

  const long NVB = (long)HH * NR * VP;   // v in bf16, VP-padded rows
  const long NF = (long)HH * NR * MF;
  const long NLT = (long)HH * LTP * MF;
  bf16* v_u = (bf16*)d_ws;
  bf16* v_i = v_u + NVB;
  bf16* qp_u = v_i + NVB;
  bf16* kp_u = qp_u + NF;
  bf16* qp_i = kp_u + NF;
  bf16* kp_i = qp_i + NF;
  bf16* ltHi_u = kp_i + NF;
  bf16* ltLo_u = ltHi_u + NLT;
  bf16* ltHi_i = ltLo_u + NLT;
  bf16* ltLo_i = ltHi_i + NLT;
  bf16* xb_u  = ltLo_i + NLT;
  bf16* xb_i  = xb_u + (long)NR * KP;
  bf16* WbTq  = xb_i + (long)NR * KP;
  bf16* WbTk  = WbTq + 4 * 256 * KP;
  bf16* WbTv  = WbTk + 4 * 256 * KP;
  bf16* WpT   = WbTv + 4 * 256 * KP;   // 8 * 64 * KP bf16
  float* part = (float*)xb_u;  // 16.4 MB split-K partials, alias xb (dead after proj4)

  cvt_x_kernel<<<dim3(NR, 2), KP, 0, stream>>>(u, ii, xb_u, xb_i);
  cvt_w_kernel<<<dim3(1024, 3), KP, 0, stream>>>(Wq, Wk, Wv, WbTq, WbTk, WbTv);
  cvt_wp_kernel<<<dim3(KP, HH, 2), 64, 0, stream>>>(Wq, Wk, bq, bk, proj, WpT);

  // zh fast (24 A-sharing blocks consecutive -> XCD L2 reuse), 64-row tiles.
  // feat fused into z>=2 blocks (qp/kp written here; fr internal to LDS).
  proj4_kernel<<<dim3(24, (NR + 63) / 64), 256, 0, stream>>>(
      xb_u, xb_i, WbTq, WbTk, WbTv, WpT, bq, bk, bv,
      v_u, v_i, qp_u, kp_u, qp_i, kp_i);

  // side 0 (-> lastT_u) uses (v_i, kp_i); side 1 (-> lastT_i) uses (v_u, kp_u)
  last3_kernel<<<dim3(5, LKC, 8), 256, 0, stream>>>(v_i, kp_i, v_u, kp_u, part);
  reduce_last4<<<dim3(LTP, 8), 64, 0, stream>>>(part, ltHi_u, ltLo_u, ltHi_i, ltLo_i);

  fuse3_kernel<<<dim3(NR / 32, 2), 256, 0, stream>>>(
      qp_u, v_u, ltHi_u, ltLo_u, qp_i, v_i, ltHi_i, ltLo_i, out);
}